// Round 1
// baseline (10714.301 us; speedup 1.0000x reference)
//
#include <hip/hip_runtime.h>
#include <math.h>

// Problem constants
#define HN 5
#define BB 8
#define LL 20480
#define DD 1024
#define MM 1024
// per-head matrix element count (B*M*D)
#define NP 8388608LL

// ---------------- helpers ----------------

__device__ __forceinline__ float mishf(float x) {
    // softplus computed stably, matches jax.nn.softplus
    float sp = x > 0.f ? x + log1pf(__expf(-x)) : log1pf(__expf(x));
    return x * tanhf(sp);
}

// 256-thread block reductions (4 waves of 64)
__device__ __forceinline__ float2 block_reduce_sum2(float s, float q, float* lds) {
#pragma unroll
    for (int o = 32; o > 0; o >>= 1) {
        s += __shfl_down(s, o, 64);
        q += __shfl_down(q, o, 64);
    }
    int lane = threadIdx.x & 63, w = threadIdx.x >> 6;
    __syncthreads();
    if (lane == 0) { lds[w * 2] = s; lds[w * 2 + 1] = q; }
    __syncthreads();
    float2 r;
    r.x = lds[0] + lds[2] + lds[4] + lds[6];
    r.y = lds[1] + lds[3] + lds[5] + lds[7];
    return r;
}

__device__ __forceinline__ float block_reduce_max(float m, float* lds) {
#pragma unroll
    for (int o = 32; o > 0; o >>= 1) m = fmaxf(m, __shfl_down(m, o, 64));
    int lane = threadIdx.x & 63, w = threadIdx.x >> 6;
    __syncthreads();
    if (lane == 0) lds[w] = m;
    __syncthreads();
    return fmaxf(fmaxf(lds[0], lds[1]), fmaxf(lds[2], lds[3]));
}

// ---------------- GEMM ----------------
// C(MxN) = epilogue(A(MxK) @ B), B row-major KxN (NN) or row-major NxK (NT)
// 128x128 tile, BK=8, 256 threads, 8x8 per-thread microtile. All dims multiples of 128.

#define BM 128
#define BN 128
#define BK 8
#define TM 8
#define TN 8

#define EPI_BIAS 0       // C = acc + bias[n]
#define EPI_SCALE 1      // C = acc * (alpha_const * (*alpha_ptr or 1))
#define EPI_BIAS_MISH 2  // C = mish(acc + bias[n])
#define EPI_ACCUM 3      // C += acc

template <bool TRANSB, int EPI>
__global__ __launch_bounds__(256) void gemm_kernel(
    const float* __restrict__ A, const float* __restrict__ Bm, float* __restrict__ C,
    const float* __restrict__ bias, const float* __restrict__ alpha_ptr, float alpha_const,
    int M, int N, int K, long long sA, long long sB, long long sC) {
    A += (long long)blockIdx.z * sA;
    Bm += (long long)blockIdx.z * sB;
    C += (long long)blockIdx.z * sC;
    const int bm = blockIdx.y * BM;
    const int bn = blockIdx.x * BN;
    __shared__ float As[BK][BM];
    __shared__ float Bs[BK][BN];
    const int tid = threadIdx.x;
    const int tx = tid & 15, ty = tid >> 4;
    const int arow = tid >> 1;         // 0..127
    const int akp = (tid & 1) * 4;     // 0 or 4
    const int brow = tid >> 5;         // 0..7
    const int bcol = (tid & 31) * 4;   // 0..124
    float acc[TM][TN] = {};

    const float* Aptr = A + (long long)(bm + arow) * K + akp;
    const float* Bptr;
    if (!TRANSB)
        Bptr = Bm + (long long)brow * N + bn + bcol;
    else
        Bptr = Bm + (long long)(bn + arow) * K + akp;

    for (int k0 = 0; k0 < K; k0 += BK) {
        float4 av = *(const float4*)(Aptr + k0);
        float4 bv;
        if (!TRANSB)
            bv = *(const float4*)(Bptr + (long long)k0 * N);
        else
            bv = *(const float4*)(Bptr + k0);
        __syncthreads();
        As[akp + 0][arow] = av.x;
        As[akp + 1][arow] = av.y;
        As[akp + 2][arow] = av.z;
        As[akp + 3][arow] = av.w;
        if (!TRANSB) {
            *(float4*)&Bs[brow][bcol] = bv;
        } else {
            Bs[akp + 0][arow] = bv.x;
            Bs[akp + 1][arow] = bv.y;
            Bs[akp + 2][arow] = bv.z;
            Bs[akp + 3][arow] = bv.w;
        }
        __syncthreads();
#pragma unroll
        for (int kk = 0; kk < BK; ++kk) {
            float a[TM], b[TN];
#pragma unroll
            for (int i = 0; i < TM; ++i) a[i] = As[kk][ty * TM + i];
#pragma unroll
            for (int j = 0; j < TN; ++j) b[j] = Bs[kk][tx * TN + j];
#pragma unroll
            for (int i = 0; i < TM; ++i)
#pragma unroll
                for (int j = 0; j < TN; ++j) acc[i][j] = fmaf(a[i], b[j], acc[i][j]);
        }
    }

    float alpha = alpha_const;
    if (EPI == EPI_SCALE && alpha_ptr) alpha *= alpha_ptr[0];

#pragma unroll
    for (int i = 0; i < TM; ++i) {
        long long row = bm + ty * TM + i;
        float* crow = C + row * (long long)N + bn + tx * TN;
        float v[TN];
#pragma unroll
        for (int j = 0; j < TN; ++j) {
            float x = acc[i][j];
            if (EPI == EPI_BIAS)
                x = x + bias[bn + tx * TN + j];
            else if (EPI == EPI_SCALE)
                x = x * alpha;
            else if (EPI == EPI_BIAS_MISH)
                x = mishf(x + bias[bn + tx * TN + j]);
            else if (EPI == EPI_ACCUM)
                x = x + crow[j];
            v[j] = x;
        }
        *(float4*)(crow) = make_float4(v[0], v[1], v[2], v[3]);
        *(float4*)(crow + 4) = make_float4(v[4], v[5], v[6], v[7]);
    }
}

// ---------------- conv (depthwise k=3, stride p) + avg-pool to 1024 + LayerNorm ----------------
// One block per (b, m) output row; 256 threads x 4 d's.
__global__ __launch_bounds__(256) void conv_pool_ln_kernel(
    const float* __restrict__ x, const float* __restrict__ cw, const float* __restrict__ cb,
    const float* __restrict__ g, const float* __restrict__ bta, float* __restrict__ P,
    int p, int G) {
    const int bm = blockIdx.x;  // b*1024 + m
    const int b = bm >> 10;
    const int m = bm & 1023;
    const int tid = threadIdx.x;
    const float invG = 1.0f / (float)G;
    const long long xbase = (long long)b * LL * DD;
    float f[4];
    float s = 0.f, q = 0.f;
#pragma unroll
    for (int u = 0; u < 4; ++u) {
        int d = tid + u * 256;
        float w0 = cw[d * 3 + 0], w1 = cw[d * 3 + 1], w2 = cw[d * 3 + 2];
        float acc = 0.f;
        for (int j0 = 0; j0 < G; ++j0) {
            int pos = (m * G + j0) * p;
            float xm = (pos - 1 >= 0) ? x[xbase + (long long)(pos - 1) * DD + d] : 0.f;
            float x0 = x[xbase + (long long)pos * DD + d];
            float xp = (pos + 1 < LL) ? x[xbase + (long long)(pos + 1) * DD + d] : 0.f;
            acc = fmaf(w0, xm, acc);
            acc = fmaf(w1, x0, acc);
            acc = fmaf(w2, xp, acc);
        }
        float val = acc * invG + cb[d];
        f[u] = val;
        s += val;
        q += val * val;
    }
    __shared__ float lds[8];
    float2 r = block_reduce_sum2(s, q, lds);
    float mean = r.x * (1.0f / 1024.0f);
    float var = r.y * (1.0f / 1024.0f) - mean * mean;
    float rstd = rsqrtf(var + 1e-5f);
    long long obase = (long long)bm * DD;
#pragma unroll
    for (int u = 0; u < 4; ++u) {
        int d = tid + u * 256;
        P[obase + d] = (f[u] - mean) * rstd * g[d] + bta[d];
    }
}

// ---------------- softmax over rows of 1024, in place ----------------
__global__ __launch_bounds__(256) void softmax_kernel(float* __restrict__ S) {
    float4* row = (float4*)(S + (long long)blockIdx.x * 1024);
    int tid = threadIdx.x;
    float4 v = row[tid];
    __shared__ float lds[8];
    float m = fmaxf(fmaxf(v.x, v.y), fmaxf(v.z, v.w));
    m = block_reduce_max(m, lds);
    v.x = __expf(v.x - m);
    v.y = __expf(v.y - m);
    v.z = __expf(v.z - m);
    v.w = __expf(v.w - m);
    float s = v.x + v.y + v.z + v.w;
    float2 r = block_reduce_sum2(s, 0.f, lds);
    float inv = 1.0f / r.x;
    v.x *= inv;
    v.y *= inv;
    v.z *= inv;
    v.w *= inv;
    row[tid] = v;
}

// ---------------- residual + LN(ff) + LN(head) fused, rows of 1024 ----------------
__global__ __launch_bounds__(256) void resid_ln2_kernel(
    const float* __restrict__ X, const float* __restrict__ Z,
    const float* __restrict__ g1, const float* __restrict__ b1,
    const float* __restrict__ g2, const float* __restrict__ b2,
    float* __restrict__ out) {
    long long base = (long long)blockIdx.x * 1024;
    int tid = threadIdx.x;
    float4 xv = ((const float4*)(X + base))[tid];
    float4 zv = ((const float4*)(Z + base))[tid];
    float r0 = xv.x + zv.x, r1 = xv.y + zv.y, r2 = xv.z + zv.z, r3 = xv.w + zv.w;
    __shared__ float lds[8];
    float s = r0 + r1 + r2 + r3;
    float q = r0 * r0 + r1 * r1 + r2 * r2 + r3 * r3;
    float2 rr = block_reduce_sum2(s, q, lds);
    float mean = rr.x * (1.f / 1024.f);
    float var = rr.y * (1.f / 1024.f) - mean * mean;
    float rstd = rsqrtf(var + 1e-5f);
    float4 g1v = ((const float4*)g1)[tid], b1v = ((const float4*)b1)[tid];
    float t0 = (r0 - mean) * rstd * g1v.x + b1v.x;
    float t1 = (r1 - mean) * rstd * g1v.y + b1v.y;
    float t2 = (r2 - mean) * rstd * g1v.z + b1v.z;
    float t3 = (r3 - mean) * rstd * g1v.w + b1v.w;
    s = t0 + t1 + t2 + t3;
    q = t0 * t0 + t1 * t1 + t2 * t2 + t3 * t3;
    rr = block_reduce_sum2(s, q, lds);
    float mean2 = rr.x * (1.f / 1024.f);
    float var2 = rr.y * (1.f / 1024.f) - mean2 * mean2;
    float rstd2 = rsqrtf(var2 + 1e-5f);
    float4 g2v = ((const float4*)g2)[tid], b2v = ((const float4*)b2)[tid];
    float4 o;
    o.x = (t0 - mean2) * rstd2 * g2v.x + b2v.x;
    o.y = (t1 - mean2) * rstd2 * g2v.y + b2v.y;
    o.z = (t2 - mean2) * rstd2 * g2v.z + b2v.z;
    o.w = (t3 - mean2) * rstd2 * g2v.w + b2v.w;
    ((float4*)(out + base))[tid] = o;
}

// ---------------- elementwise ----------------
__global__ __launch_bounds__(256) void mish_kernel(const float* __restrict__ in,
                                                   float* __restrict__ out) {
    long long i = (long long)blockIdx.x * 256 + threadIdx.x;  // over float4s, exact
    float4 v = ((const float4*)in)[i];
    v.x = mishf(v.x);
    v.y = mishf(v.y);
    v.z = mishf(v.z);
    v.w = mishf(v.w);
    ((float4*)out)[i] = v;
}

__global__ __launch_bounds__(256) void init_out_kernel(float* __restrict__ out,
                                                       const float* __restrict__ pb) {
    long long i = (long long)blockIdx.x * 256 + threadIdx.x;  // float4 index
    float4 v = ((const float4*)pb)[i & 255];                  // 256 float4 per 1024-row
    ((float4*)out)[i] = v;
}

__global__ __launch_bounds__(256) void add_kernel(float* __restrict__ out,
                                                  const float* __restrict__ P) {
    long long i = (long long)blockIdx.x * 256 + threadIdx.x;
    float4 a = ((float4*)out)[i];
    float4 b = ((const float4*)P)[i];
    a.x += b.x;
    a.y += b.y;
    a.z += b.z;
    a.w += b.w;
    ((float4*)out)[i] = a;
}

// ---------------- launch ----------------
extern "C" void kernel_launch(void* const* d_in, const int* in_sizes, int n_in,
                              void* d_out, int out_size, void* d_ws, size_t ws_size,
                              hipStream_t stream) {
    const float* value = (const float*)d_in[0];
    const float* conv_w = (const float*)d_in[1];
    const float* conv_b = (const float*)d_in[2];
    const float* q_w = (const float*)d_in[3];
    const float* q_b = (const float*)d_in[4];
    const float* k_w = (const float*)d_in[5];
    const float* k_b = (const float*)d_in[6];
    const float* v_w = (const float*)d_in[7];
    const float* v_b = (const float*)d_in[8];
    const float* scale = (const float*)d_in[9];
    const float* ff_w1 = (const float*)d_in[10];
    const float* ff_b1 = (const float*)d_in[11];
    const float* ff_w2 = (const float*)d_in[12];
    const float* ff_b2 = (const float*)d_in[13];
    const float* ff_ln_g = (const float*)d_in[14];
    const float* ff_ln_b = (const float*)d_in[15];
    const float* norm_g = (const float*)d_in[16];
    const float* norm_b = (const float*)d_in[17];
    const float* norm_in_g = (const float*)d_in[18];
    const float* norm_in_b = (const float*)d_in[19];
    const float* proj_w = (const float*)d_in[20];
    const float* proj_b = (const float*)d_in[21];

    float* out = (float*)d_out;
    float* attn0 = out + NP;  // (5,8,1024,1024) region

    float* ws = (float*)d_ws;
    float* P = ws;            // projected (current head; last head's kept for final add)
    float* Qb = P + NP;
    float* Kb = Qb + NP;
    float* Vb = Kb + NP;
    float* O1 = Vb + NP;

    dim3 blk(256);
    const long long n4 = NP / 4;  // 2097152 float4s -> 8192 blocks
    init_out_kernel<<<(int)(n4 / 256), blk, 0, stream>>>(out, proj_b);

    const int periods[5] = {2, 4, 5, 10, 20};
    for (int h = 0; h < 5; ++h) {
        int p = periods[h], G = 20 / p;
        conv_pool_ln_kernel<<<8192, blk, 0, stream>>>(
            value, conv_w + h * 3072, conv_b + h * 1024, norm_in_g, norm_in_b, P, p, G);

        dim3 g1(8, 64, 1);  // N/128, M/128 for M=8192
        gemm_kernel<false, EPI_BIAS><<<g1, blk, 0, stream>>>(
            P, q_w + (long long)h * 1048576, Qb, q_b + h * 1024, nullptr, 1.f,
            8192, 1024, 1024, 0, 0, 0);
        gemm_kernel<false, EPI_BIAS><<<g1, blk, 0, stream>>>(
            P, k_w + (long long)h * 1048576, Kb, k_b + h * 1024, nullptr, 1.f,
            8192, 1024, 1024, 0, 0, 0);
        gemm_kernel<false, EPI_BIAS><<<g1, blk, 0, stream>>>(
            P, v_w + (long long)h * 1048576, Vb, v_b + h * 1024, nullptr, 1.f,
            8192, 1024, 1024, 0, 0, 0);

        float* Sh = attn0 + (long long)h * NP;
        dim3 g2(8, 8, 8);  // batched over B
        // S = Q @ K^T * (1/32)
        gemm_kernel<true, EPI_SCALE><<<g2, blk, 0, stream>>>(
            Qb, Kb, Sh, nullptr, nullptr, 0.03125f,
            1024, 1024, 1024, 1048576, 1048576, 1048576);
        softmax_kernel<<<8192, blk, 0, stream>>>(Sh);
        // O1 = scale[h] * (attn @ V)
        gemm_kernel<false, EPI_SCALE><<<g2, blk, 0, stream>>>(
            Sh, Vb, O1, nullptr, scale + h, 1.f,
            1024, 1024, 1024, 1048576, 1048576, 1048576);

        // FF: z1 = mish(O1) -> Qb ; z2 = mish(z1@w1+b1) -> Kb ; z3 = mish(z2@w2+b2) -> Qb
        mish_kernel<<<(int)(n4 / 256), blk, 0, stream>>>(O1, Qb);
        gemm_kernel<false, EPI_BIAS_MISH><<<g1, blk, 0, stream>>>(
            Qb, ff_w1, Kb, ff_b1, nullptr, 1.f, 8192, 1024, 1024, 0, 0, 0);
        gemm_kernel<false, EPI_BIAS_MISH><<<g1, blk, 0, stream>>>(
            Kb, ff_w2, Qb, ff_b2, nullptr, 1.f, 8192, 1024, 1024, 0, 0, 0);
        // HO = LN(LN(O1 + z3, ff), norm) -> Kb
        resid_ln2_kernel<<<8192, blk, 0, stream>>>(O1, Qb, ff_ln_g, ff_ln_b, norm_g, norm_b, Kb);
        // out += HO @ proj_w[h*1024:(h+1)*1024, :]
        gemm_kernel<false, EPI_ACCUM><<<g1, blk, 0, stream>>>(
            Kb, proj_w + (long long)h * 1048576, out, nullptr, nullptr, 1.f,
            8192, 1024, 1024, 0, 0, 0);
    }
    // out += projected (last head's, loop-variable leak in reference)
    add_kernel<<<(int)(n4 / 256), blk, 0, stream>>>(out, P);
}